// Round 8
// baseline (165.896 us; speedup 1.0000x reference)
//
#include <hip/hip_runtime.h>

// Project2Dto3D: out[b,c,v] = sum over pixels hw with proj[hw]==v of feat[b,c,hw]
// B=4, C=128, H=240, W=320, V=60*36*60=129600
//
// CSR build -> fused transpose+permute+rank to channel-last featP[j][bc] (bf16)
// -> streaming gather (f32 accumulate) shaped 64ch x 160vox so NT output
// writes land in 640B contiguous runs per bc-row (DRAM-page friendly).

static constexpr int HW = 240 * 320;      // 76800
static constexpr int V  = 60 * 36 * 60;   // 129600
static constexpr int B  = 4;
static constexpr int C  = 128;
static constexpr int BC = B * C;          // 512
static constexpr int NBV = (V + 255) / 256;    // 507
static constexpr int NHWT = HW / 64;      // 1200 hw-tiles

static constexpr int VT   = 160;          // voxels per gather block
static constexpr int BCB  = 64;           // channels per gather block
static constexpr int NGX  = V / VT;       // 810
static constexpr int NGY  = BC / BCB;     // 8
static constexpr int VPG  = VT / 8;       // 20 voxels per thread-group

typedef float f4 __attribute__((ext_vector_type(4)));

static __device__ __forceinline__ unsigned short f2bf(float x) {
    unsigned int u = __builtin_bit_cast(unsigned int, x);
    unsigned int r = (u + 0x7FFFu + ((u >> 16) & 1u)) >> 16;   // RNE
    return (unsigned short)r;
}
static __device__ __forceinline__ float bf2f(unsigned short s) {
    unsigned int u = ((unsigned int)s) << 16;
    return __builtin_bit_cast(float, u);
}

// ---------------------------------------------------------------------------
__global__ void __launch_bounds__(256) zero_kernel(int* __restrict__ cnt) {
    int i = blockIdx.x * 256 + threadIdx.x;
    if (i < V) cnt[i] = 0;
}

__global__ void __launch_bounds__(256) count_kernel(const int* __restrict__ idx,
                                                    int* __restrict__ cnt) {
    int hw = blockIdx.x * 256 + threadIdx.x;
    if (hw < HW) atomicAdd(&cnt[idx[hw]], 1);
}

__global__ void __launch_bounds__(256) blocksum_kernel(const int* __restrict__ cnt,
                                                       int* __restrict__ bsum) {
    int i = blockIdx.x * 256 + threadIdx.x;
    int v = (i < V) ? cnt[i] : 0;
#pragma unroll
    for (int d = 32; d > 0; d >>= 1) v += __shfl_down(v, d, 64);
    __shared__ int ws[4];
    if ((threadIdx.x & 63) == 0) ws[threadIdx.x >> 6] = v;
    __syncthreads();
    if (threadIdx.x == 0) bsum[blockIdx.x] = ws[0] + ws[1] + ws[2] + ws[3];
}

__global__ void __launch_bounds__(512) scan_bsum_kernel(int* __restrict__ bsum) {
    __shared__ int sm[512];
    int t = threadIdx.x;
    int v = (t < NBV) ? bsum[t] : 0;
    sm[t] = v;
    __syncthreads();
    for (int d = 1; d < 512; d <<= 1) {
        int x = (t >= d) ? sm[t - d] : 0;
        __syncthreads();
        sm[t] += x;
        __syncthreads();
    }
    if (t < NBV) bsum[t] = sm[t] - v;   // exclusive
}

// off (= cnt, in place) becomes exclusive offsets; cursor copies; off[V]=HW sentinel
__global__ void __launch_bounds__(256) scatter_off_kernel(int* __restrict__ cnt,
                                                          const int* __restrict__ bsum,
                                                          int* __restrict__ cursor) {
    int i = blockIdx.x * 256 + threadIdx.x;
    int c = (i < V) ? cnt[i] : 0;
    int lane = threadIdx.x & 63, w = threadIdx.x >> 6;
    int inc = c;
#pragma unroll
    for (int d = 1; d < 64; d <<= 1) {
        int x = __shfl_up(inc, d, 64);
        if (lane >= d) inc += x;
    }
    __shared__ int wsum[4];
    if (lane == 63) wsum[w] = inc;
    __syncthreads();
    int woff = 0;
    for (int k = 0; k < w; ++k) woff += wsum[k];
    int excl = inc - c + woff + bsum[blockIdx.x];
    if (i < V) { cnt[i] = excl; cursor[i] = excl; }
    if (i == 0) cnt[V] = HW;
}

// Fused rank + transpose + f32->bf16 pack. One block per 64-pixel hw-tile:
// ranks computed once (atomicAdd on cursor), reused across all 8 bc-tiles.
// Loads: f4 (256B per 16-lane group). Stores: uint4 = 8 bf16, 128B contiguous
// per dst row.
__global__ void __launch_bounds__(512) transpose_perm_kernel(
        const float* __restrict__ feat, const int* __restrict__ idx,
        int* __restrict__ cursor, unsigned short* __restrict__ featP) {
    __shared__ float tile[64][65];
    __shared__ int rk[64];
    int hw0 = blockIdx.x * 64;
    int t   = threadIdx.x;

    if (t < 64) {
        int v = idx[hw0 + t];
        rk[t] = atomicAdd(&cursor[v], 1);   // global CSR slot
    }

    for (int by = 0; by < NGY; ++by) {
        int bc0 = by * 64;
        // load 64 bc-rows x 16 f4 = 1024 units, 2 per thread
#pragma unroll
        for (int k = 0; k < 2; ++k) {
            int u  = k * 512 + t;
            int r  = u >> 4;         // bc row 0..63
            int cq = u & 15;         // f4 col
            f4 v = *(const f4*)(feat + (long long)(bc0 + r) * HW + hw0 + 4 * cq);
            tile[r][4 * cq + 0] = v.x;
            tile[r][4 * cq + 1] = v.y;
            tile[r][4 * cq + 2] = v.z;
            tile[r][4 * cq + 3] = v.w;
        }
        __syncthreads();             // also covers rk on first iteration
        {
            int h = t >> 3;          // hw row 0..63
            int q = t & 7;           // 8-channel pack
            union { unsigned short us[8]; uint4 v4; } p;
#pragma unroll
            for (int i = 0; i < 8; ++i)
                p.us[i] = f2bf(tile[8 * q + i][h]);
            *(uint4*)(featP + (long long)rk[h] * BC + bc0 + 8 * q) = p.v4;
        }
        __syncthreads();             // before next bc-tile overwrites `tile`
    }
}

// Gather: block = (160 voxels, 64 channels). Wave-uniform segment loops,
// 128B coalesced featP reads; LDS-staged output so each NT store row is a
// 640B contiguous run (16B/lane x 40 lanes per bc-row).
__global__ void __launch_bounds__(512, 6) gatherT_kernel(
        const unsigned short* __restrict__ featP, const int* __restrict__ off,
        float* __restrict__ out) {
    __shared__ float sm[VT][BCB + 1];
    int v0  = blockIdx.x * VT;
    int bc0 = blockIdx.y * BCB;
    int t   = threadIdx.x;
    int bcl = t & 63;
    int grp = t >> 6;                // 0..7
    int vb  = grp * VPG;

    float acc[VPG];
#pragma unroll
    for (int i = 0; i < VPG; ++i) {
        int j0 = off[v0 + vb + i];
        int j1 = off[v0 + vb + i + 1];
        float a = 0.f;
        for (int j = j0; j < j1; ++j)
            a += bf2f(featP[(long long)j * BC + bc0 + bcl]);
        acc[i] = a;
    }
#pragma unroll
    for (int i = 0; i < VPG; ++i) sm[vb + i][bcl] = acc[i];
    __syncthreads();

    // write: 64 bc-rows x 40 f4-units = 2560 units, 5 per thread
#pragma unroll
    for (int w = 0; w < 5; ++w) {
        int u = w * 512 + t;
        int r = u / 40;              // bc row 0..63
        int k = u % 40;              // f4 index along v
        f4 val = { sm[4 * k + 0][r], sm[4 * k + 1][r],
                   sm[4 * k + 2][r], sm[4 * k + 3][r] };
        __builtin_nontemporal_store(val,
            (f4*)(out + (long long)(bc0 + r) * V + v0 + 4 * k));
    }
}

// ---------------------------------------------------------------------------
// Fallback (round-3 path, f32 direct from feat) if workspace too small.
static constexpr int BCPT = 8;
static constexpr int NG = BC / BCPT;
static constexpr int NXCD = 8;
static constexpr int GPX = NG / NXCD;

__global__ void __launch_bounds__(256) perm_kernel(const int* __restrict__ idx,
                                                   int* __restrict__ cursor,
                                                   int* __restrict__ perm) {
    int hw = blockIdx.x * 256 + threadIdx.x;
    if (hw < HW) {
        int v = idx[hw];
        int pos = atomicAdd(&cursor[v], 1);
        perm[pos] = hw;
    }
}

__global__ void __launch_bounds__(256) gather_kernel(const float* __restrict__ feat,
                                                     const int* __restrict__ off,
                                                     const int* __restrict__ perm,
                                                     float* __restrict__ out) {
    int bid  = blockIdx.x;
    int xcd  = bid & (NXCD - 1);
    int lid  = bid >> 3;
    int gloc = lid / NBV;
    int vblk = lid - gloc * NBV;
    int g    = xcd * GPX + gloc;
    int v    = vblk * 256 + threadIdx.x;
    if (v >= V) return;
    int bc0 = g * BCPT;
    int j0 = off[v];
    int j1 = off[v + 1];
    const float* f = feat + (long long)bc0 * HW;
    float s[BCPT];
#pragma unroll
    for (int k = 0; k < BCPT; ++k) s[k] = 0.f;
    for (int j = j0; j < j1; ++j) {
        int p = perm[j];
#pragma unroll
        for (int k = 0; k < BCPT; ++k) s[k] += f[p + k * HW];
    }
    long long o = (long long)bc0 * V + v;
#pragma unroll
    for (int k = 0; k < BCPT; ++k)
        __builtin_nontemporal_store(s[k], &out[o + (long long)k * V]);
}

extern "C" void kernel_launch(void* const* d_in, const int* in_sizes, int n_in,
                              void* d_out, int out_size, void* d_ws, size_t ws_size,
                              hipStream_t stream) {
    const float* feat = (const float*)d_in[0];   // [4,128,240,320] f32
    const int*   idx  = (const int*)d_in[1];     // [240,320] int
    float*       out  = (float*)d_out;           // [4,128,129600] f32

    // workspace: off[V+1] | cursor[V] | perm[HW] (fallback only) | bsum[512] | featP (bf16)
    int* off    = (int*)d_ws;
    int* cursor = off + (V + 1);
    int* perm   = cursor + V;
    int* bsum   = perm + HW;
    size_t hdr_bytes = ((size_t)(V + 1 + V + HW + 512) * 4 + 255) & ~(size_t)255;
    unsigned short* featP = (unsigned short*)((char*)d_ws + hdr_bytes);
    size_t need = hdr_bytes + (size_t)HW * BC * sizeof(unsigned short);

    zero_kernel       <<<NBV, 256, 0, stream>>>(off);
    count_kernel      <<<(HW + 255) / 256, 256, 0, stream>>>(idx, off);
    blocksum_kernel   <<<NBV, 256, 0, stream>>>(off, bsum);
    scan_bsum_kernel  <<<1, 512, 0, stream>>>(bsum);
    scatter_off_kernel<<<NBV, 256, 0, stream>>>(off, bsum, cursor);

    if (ws_size >= need) {
        transpose_perm_kernel<<<NHWT, 512, 0, stream>>>(feat, idx, cursor, featP);
        dim3 ggrid(NGX, NGY);
        gatherT_kernel<<<ggrid, 512, 0, stream>>>(featP, off, out);
    } else {
        perm_kernel<<<(HW + 255) / 256, 256, 0, stream>>>(idx, cursor, perm);
        gather_kernel<<<NXCD * GPX * NBV, 256, 0, stream>>>(feat, off, perm, out);
    }
}

// Round 9
// 136.931 us; speedup vs baseline: 1.2115x; 1.2115x over previous
//
#include <hip/hip_runtime.h>

// Project2Dto3D: out[b,c,v] = sum over pixels hw with proj[hw]==v of feat[b,c,hw]
// B=4, C=128, H=240, W=320, V=60*36*60=129600
//
// CSR build (count -> fused scan -> fused rank) -> transpose+permute to
// channel-last featP[j][bc] (bf16) -> balanced-walk gather (f32 accumulate)
// with LDS-staged full-line output writes.

static constexpr int HW = 240 * 320;      // 76800
static constexpr int V  = 60 * 36 * 60;   // 129600
static constexpr int B  = 4;
static constexpr int C  = 128;
static constexpr int BC = B * C;          // 512
static constexpr int NBV = (V + 255) / 256;    // 507
static constexpr int NHWT = HW / 64;      // 1200 hw-tiles
static constexpr int NGY  = BC / 64;      // 8 bc-tiles
static constexpr int VT = 16;             // voxels per gather tile
static constexpr int NVT = V / VT;        // 8100
static constexpr int SMP = BC + 1;        // padded LDS row stride (513)

typedef float f4 __attribute__((ext_vector_type(4)));

static __device__ __forceinline__ unsigned short f2bf(float x) {
    unsigned int u = __builtin_bit_cast(unsigned int, x);
    unsigned int r = (u + 0x7FFFu + ((u >> 16) & 1u)) >> 16;   // RNE
    return (unsigned short)r;
}
static __device__ __forceinline__ float bf2f(unsigned short s) {
    unsigned int u = ((unsigned int)s) << 16;
    return __builtin_bit_cast(float, u);
}

// ---------------------------------------------------------------------------
__global__ void __launch_bounds__(256) zero_kernel(int* __restrict__ cnt) {
    int i = blockIdx.x * 256 + threadIdx.x;
    if (i < V) cnt[i] = 0;
}

__global__ void __launch_bounds__(256) count_kernel(const int* __restrict__ idx,
                                                    int* __restrict__ cnt) {
    int hw = blockIdx.x * 256 + threadIdx.x;
    if (hw < HW) atomicAdd(&cnt[idx[hw]], 1);
}

__global__ void __launch_bounds__(256) blocksum_kernel(const int* __restrict__ cnt,
                                                       int* __restrict__ bsum) {
    int i = blockIdx.x * 256 + threadIdx.x;
    int v = (i < V) ? cnt[i] : 0;
#pragma unroll
    for (int d = 32; d > 0; d >>= 1) v += __shfl_down(v, d, 64);
    __shared__ int ws[4];
    if ((threadIdx.x & 63) == 0) ws[threadIdx.x >> 6] = v;
    __syncthreads();
    if (threadIdx.x == 0) bsum[blockIdx.x] = ws[0] + ws[1] + ws[2] + ws[3];
}

// Scan fused into scatter: each block computes its own prefix over bsum
// (507 x 4B, L2-broadcast), then the in-block exclusive scan.
// off (= cnt, in place) becomes exclusive offsets; cursor copies; off[V]=HW.
__global__ void __launch_bounds__(256) scatter_off_kernel(int* __restrict__ cnt,
                                                          const int* __restrict__ bsum,
                                                          int* __restrict__ cursor) {
    int t = threadIdx.x;
    int i = blockIdx.x * 256 + t;

    // --- block prefix: sum of bsum[0 .. blockIdx.x) ---
    int pre = 0;
    for (int u = t; u < NBV; u += 256)
        if (u < blockIdx.x) pre += bsum[u];
#pragma unroll
    for (int d = 32; d > 0; d >>= 1) pre += __shfl_down(pre, d, 64);
    __shared__ int ps[4];
    if ((t & 63) == 0) ps[t >> 6] = pre;
    __syncthreads();
    int blockoff = ps[0] + ps[1] + ps[2] + ps[3];

    // --- in-block exclusive scan of 256 counts ---
    int c = (i < V) ? cnt[i] : 0;
    int lane = t & 63, w = t >> 6;
    int inc = c;
#pragma unroll
    for (int d = 1; d < 64; d <<= 1) {
        int x = __shfl_up(inc, d, 64);
        if (lane >= d) inc += x;
    }
    __shared__ int wsum[4];
    if (lane == 63) wsum[w] = inc;
    __syncthreads();
    int woff = 0;
    for (int k = 0; k < w; ++k) woff += wsum[k];
    int excl = inc - c + woff + blockoff;
    if (i < V) { cnt[i] = excl; cursor[i] = excl; }
    if (i == 0) cnt[V] = HW;
}

// Fused rank + transpose + f32->bf16 pack. One block per 64-pixel hw-tile:
// ranks computed once (atomicAdd on cursor), reused across all 8 bc-tiles.
__global__ void __launch_bounds__(512) transpose_perm_kernel(
        const float* __restrict__ feat, const int* __restrict__ idx,
        int* __restrict__ cursor, unsigned short* __restrict__ featP) {
    __shared__ float tile[64][65];
    __shared__ int rk[64];
    int hw0 = blockIdx.x * 64;
    int t   = threadIdx.x;

    if (t < 64) {
        int v = idx[hw0 + t];
        rk[t] = atomicAdd(&cursor[v], 1);   // global CSR slot
    }

    for (int by = 0; by < NGY; ++by) {
        int bc0 = by * 64;
#pragma unroll
        for (int k = 0; k < 2; ++k) {
            int u  = k * 512 + t;
            int r  = u >> 4;         // bc row 0..63
            int cq = u & 15;         // f4 col
            f4 v = *(const f4*)(feat + (long long)(bc0 + r) * HW + hw0 + 4 * cq);
            tile[r][4 * cq + 0] = v.x;
            tile[r][4 * cq + 1] = v.y;
            tile[r][4 * cq + 2] = v.z;
            tile[r][4 * cq + 3] = v.w;
        }
        __syncthreads();             // also covers rk on first iteration
        {
            int h = t >> 3;          // hw row 0..63
            int q = t & 7;           // 8-channel pack
            union { unsigned short us[8]; uint4 v4; } p;
#pragma unroll
            for (int i = 0; i < 8; ++i)
                p.us[i] = f2bf(tile[8 * q + i][h]);
            *(uint4*)(featP + (long long)rk[h] * BC + bc0 + 8 * q) = p.v4;
        }
        __syncthreads();             // before next bc-tile overwrites `tile`
    }
}

// Gather (r7 proven shape): block = 16-voxel tile, 512 threads, thread t =
// channel bc=t. ALL threads walk ALL 16 segments -> perfectly balanced.
// featP rows contiguous [off[v0], off[v0+16)) -> 128B coalesced reads.
// Output staged through LDS so every store instruction covers full 64B lines.
__global__ void __launch_bounds__(512) gatherT_kernel(
        const unsigned short* __restrict__ featP, const int* __restrict__ off,
        float* __restrict__ out) {
    __shared__ float sm[VT][SMP];
    int v0 = blockIdx.x * VT;
    int t = threadIdx.x;
    float acc[VT];
    int jprev = off[v0];
#pragma unroll
    for (int i = 0; i < VT; ++i) {
        int j1 = off[v0 + i + 1];
        float a = 0.f;
        for (int j = jprev; j < j1; ++j)
            a += bf2f(featP[(long long)j * BC + t]);
        acc[i] = a;
        jprev = j1;
    }
#pragma unroll
    for (int i = 0; i < VT; ++i) sm[i][t] = acc[i];
    __syncthreads();

    // Write phase: element e in [0, 512*4): bc = e>>2, vq = e&3.
#pragma unroll
    for (int r = 0; r < 4; ++r) {
        int e  = r * 512 + t;
        int bc = e >> 2;
        int vq = e & 3;
        f4 val = { sm[vq * 4 + 0][bc], sm[vq * 4 + 1][bc],
                   sm[vq * 4 + 2][bc], sm[vq * 4 + 3][bc] };
        __builtin_nontemporal_store(val, (f4*)(out + (long long)bc * V + v0 + vq * 4));
    }
}

// ---------------------------------------------------------------------------
// Fallback (round-3 path, f32 direct from feat) if workspace too small.
static constexpr int BCPT = 8;
static constexpr int NG = BC / BCPT;
static constexpr int NXCD = 8;
static constexpr int GPX = NG / NXCD;

__global__ void __launch_bounds__(256) perm_kernel(const int* __restrict__ idx,
                                                   int* __restrict__ cursor,
                                                   int* __restrict__ perm) {
    int hw = blockIdx.x * 256 + threadIdx.x;
    if (hw < HW) {
        int v = idx[hw];
        int pos = atomicAdd(&cursor[v], 1);
        perm[pos] = hw;
    }
}

__global__ void __launch_bounds__(256) gather_kernel(const float* __restrict__ feat,
                                                     const int* __restrict__ off,
                                                     const int* __restrict__ perm,
                                                     float* __restrict__ out) {
    int bid  = blockIdx.x;
    int xcd  = bid & (NXCD - 1);
    int lid  = bid >> 3;
    int gloc = lid / NBV;
    int vblk = lid - gloc * NBV;
    int g    = xcd * GPX + gloc;
    int v    = vblk * 256 + threadIdx.x;
    if (v >= V) return;
    int bc0 = g * BCPT;
    int j0 = off[v];
    int j1 = off[v + 1];
    const float* f = feat + (long long)bc0 * HW;
    float s[BCPT];
#pragma unroll
    for (int k = 0; k < BCPT; ++k) s[k] = 0.f;
    for (int j = j0; j < j1; ++j) {
        int p = perm[j];
#pragma unroll
        for (int k = 0; k < BCPT; ++k) s[k] += f[p + k * HW];
    }
    long long o = (long long)bc0 * V + v;
#pragma unroll
    for (int k = 0; k < BCPT; ++k)
        __builtin_nontemporal_store(s[k], &out[o + (long long)k * V]);
}

extern "C" void kernel_launch(void* const* d_in, const int* in_sizes, int n_in,
                              void* d_out, int out_size, void* d_ws, size_t ws_size,
                              hipStream_t stream) {
    const float* feat = (const float*)d_in[0];   // [4,128,240,320] f32
    const int*   idx  = (const int*)d_in[1];     // [240,320] int
    float*       out  = (float*)d_out;           // [4,128,129600] f32

    // workspace: off[V+1] | cursor[V] | perm[HW] (fallback) | bsum[512] | featP (bf16)
    int* off    = (int*)d_ws;
    int* cursor = off + (V + 1);
    int* perm   = cursor + V;
    int* bsum   = perm + HW;
    size_t hdr_bytes = ((size_t)(V + 1 + V + HW + 512) * 4 + 255) & ~(size_t)255;
    unsigned short* featP = (unsigned short*)((char*)d_ws + hdr_bytes);
    size_t need = hdr_bytes + (size_t)HW * BC * sizeof(unsigned short);

    zero_kernel       <<<NBV, 256, 0, stream>>>(off);
    count_kernel      <<<(HW + 255) / 256, 256, 0, stream>>>(idx, off);
    blocksum_kernel   <<<NBV, 256, 0, stream>>>(off, bsum);
    scatter_off_kernel<<<NBV, 256, 0, stream>>>(off, bsum, cursor);

    if (ws_size >= need) {
        transpose_perm_kernel<<<NHWT, 512, 0, stream>>>(feat, idx, cursor, featP);
        gatherT_kernel<<<NVT, 512, 0, stream>>>(featP, off, out);
    } else {
        perm_kernel<<<(HW + 255) / 256, 256, 0, stream>>>(idx, cursor, perm);
        gather_kernel<<<NXCD * GPX * NBV, 256, 0, stream>>>(feat, off, perm, out);
    }
}